// Round 3
// baseline (317.875 us; speedup 1.0000x reference)
//
#include <hip/hip_runtime.h>
#include <hip/hip_bf16.h>

#pragma clang fp contract(off)

#define NN   230400   // H*W*A
#define NK   128      // gt boxes
#define HW_  25600    // H*W
#define NA   9
#define NBLK 900      // NN/256
#define CCHUNK 512    // anchors per k_col block

// ---- scalar slots in ws ----
enum { S_CNT_FG=0, S_CNT_BG, S_FG_ACTIVE, S_FG_BIN, S_FG_REM, S_FG_TH, S_NFG_FINAL,
       S_BG_ACTIVE, S_BG_BIN, S_BG_REM, S_BG_TH, S_BG_K, S_NUM_EX, S_SMIN, S_WL };

__device__ __forceinline__ unsigned encf(float f) {
    unsigned u = __float_as_uint(f);
    return (u & 0x80000000u) ? ~u : (u | 0x80000000u);
}
__device__ __forceinline__ float decf(unsigned e) {
    unsigned u = (e & 0x80000000u) ? (e & 0x7FFFFFFFu) : ~e;
    return __uint_as_float(u);
}

__global__ __launch_bounds__(256) void k_init(unsigned* __restrict__ p, int n) {
    int i = blockIdx.x * blockDim.x + threadIdx.x;
    for (; i < n; i += gridDim.x * blockDim.x) p[i] = 0u;
}

// Row pass: thread = anchor (x2), loop over 128 gts in LDS. No shuffles.
__global__ __launch_bounds__(256) void k_row(
    const float4* __restrict__ anchors, const float4* __restrict__ gt,
    const float* __restrict__ iminfo, float* __restrict__ maxov,
    unsigned char* __restrict__ argm) {
    __shared__ float4 sg[NK];
    __shared__ float  sga[NK];
    int t = threadIdx.x;
    if (t < NK) {
        float4 g = gt[t];
        sg[t] = g;
        sga[t] = (g.z - g.x + 1.0f) * (g.w - g.y + 1.0f);
    }
    __syncthreads();
    int i0 = blockIdx.x * 512 + t, i1 = i0 + 256;
    float4 a0 = anchors[i0], a1 = anchors[i1];
    float imh = iminfo[0], imw = iminfo[1];
    bool in0 = (a0.x >= 0.0f) && (a0.y >= 0.0f) && (a0.z < imw) && (a0.w < imh);
    bool in1 = (a1.x >= 0.0f) && (a1.y >= 0.0f) && (a1.z < imw) && (a1.w < imh);
    float ba0 = (a0.z - a0.x + 1.0f) * (a0.w - a0.y + 1.0f);
    float ba1 = (a1.z - a1.x + 1.0f) * (a1.w - a1.y + 1.0f);
    float b0 = -INFINITY, b1 = -INFINITY;
    int x0 = 0, x1 = 0;
    for (int k = 0; k < NK; ++k) {
        float4 g = sg[k];
        float ga = sga[k];
        float iw0 = fmaxf(fminf(a0.z, g.z) - fmaxf(a0.x, g.x) + 1.0f, 0.0f);
        float ih0 = fmaxf(fminf(a0.w, g.w) - fmaxf(a0.y, g.y) + 1.0f, 0.0f);
        float it0 = iw0 * ih0;
        float v0 = it0 / (ba0 + ga - it0);
        float ov0 = in0 ? v0 : -1.0f;
        if (ov0 > b0) { b0 = ov0; x0 = k; }       // strict > => first max (jnp.argmax)
        float iw1 = fmaxf(fminf(a1.z, g.z) - fmaxf(a1.x, g.x) + 1.0f, 0.0f);
        float ih1 = fmaxf(fminf(a1.w, g.w) - fmaxf(a1.y, g.y) + 1.0f, 0.0f);
        float it1 = iw1 * ih1;
        float v1 = it1 / (ba1 + ga - it1);
        float ov1 = in1 ? v1 : -1.0f;
        if (ov1 > b1) { b1 = ov1; x1 = k; }
    }
    maxov[i0] = b0; argm[i0] = (unsigned char)x0;   // inside <=> maxov >= 0
    maxov[i1] = b1; argm[i1] = (unsigned char)x1;
}

// Column pass: thread = gt column (k = t&127, anchor-half = t>>7). No shuffles.
__global__ __launch_bounds__(256) void k_col(
    const float4* __restrict__ anchors, const float4* __restrict__ gt,
    const float* __restrict__ iminfo, unsigned* __restrict__ gtm) {
    __shared__ float4 sa[CCHUNK];
    __shared__ float  sba[CCHUNK];       // ba, or -1 flag if outside
    __shared__ float  sm[2][NK];
    int t = threadIdx.x;
    int k = t & 127, h = t >> 7;
    float4 g = gt[k];
    float ga = (g.z - g.x + 1.0f) * (g.w - g.y + 1.0f);
    float imh = iminfo[0], imw = iminfo[1];
    int base = blockIdx.x * CCHUNK;
    for (int j = t; j < CCHUNK; j += 256) {
        float4 a = anchors[base + j];
        sa[j] = a;
        bool ins = (a.x >= 0.0f) && (a.y >= 0.0f) && (a.z < imw) && (a.w < imh);
        float ba = (a.z - a.x + 1.0f) * (a.w - a.y + 1.0f);
        sba[j] = ins ? ba : -1.0f;       // outside anchors never set a column max
    }
    __syncthreads();
    float run = -1.0f;
    int j0 = h * 256;
    for (int j = 0; j < 256; ++j) {
        float4 a = sa[j0 + j];           // same addr across lanes -> LDS broadcast
        float ba = sba[j0 + j];
        float iw = fmaxf(fminf(a.z, g.z) - fmaxf(a.x, g.x) + 1.0f, 0.0f);
        float ih = fmaxf(fminf(a.w, g.w) - fmaxf(a.y, g.y) + 1.0f, 0.0f);
        float it = iw * ih;
        float v = it / (ba + ga - it);
        float ov = (ba < 0.0f) ? -1.0f : v;
        run = fmaxf(run, ov);
    }
    sm[h][k] = run;
    __syncthreads();
    if (t < NK) {
        unsigned e = encf(fmaxf(sm[0][t], sm[1][t]));
        if (e > gtm[t]) atomicMax(&gtm[t], e);   // racy prefilter; atomic authoritative
    }
}

// Sort columns ascending by gt_max (ties by index) + publish smin. 1 block.
__global__ __launch_bounds__(128) void k_sortgt(
    const float4* __restrict__ gt, const unsigned* __restrict__ gtm,
    float4* __restrict__ sgt, float* __restrict__ sgar, float* __restrict__ sgmv,
    unsigned* __restrict__ sc) {
    __shared__ unsigned se[NK];
    int t = threadIdx.x;
    unsigned e = gtm[t];
    se[t] = e;
    __syncthreads();
    int rank = 0;
    for (int j = 0; j < NK; ++j) {
        unsigned ej = se[j];
        rank += (ej < e) || (ej == e && j < t);
    }
    float4 g = gt[t];
    float val = decf(e);
    sgt[rank]  = g;
    sgar[rank] = (g.z - g.x + 1.0f) * (g.w - g.y + 1.0f);
    sgmv[rank] = val;
    if (rank == 0) sc[S_SMIN] = __float_as_uint(val);
}

// Labels pass A: loop-free. Final labels for non-candidates + their counts/hists.
// Candidates (smin <= mo < 0.7, inside) appended to worklist (wave-aggregated).
__global__ __launch_bounds__(256) void k_labels_a(
    const float* __restrict__ maxov, const float* __restrict__ noise,
    unsigned* __restrict__ sc, float* __restrict__ labels,
    unsigned* __restrict__ hfh, unsigned* __restrict__ hbh,
    unsigned* __restrict__ wl) {
    int t = threadIdx.x;
    int i = blockIdx.x * 256 + t;
    float mo = maxov[i];
    bool ins = mo >= 0.0f;
    float smin = __uint_as_float(sc[S_SMIN]);
    float lab = -1.0f;
    if (ins && mo < 0.3f)  lab = 0.0f;
    if (ins && mo >= 0.7f) lab = 1.0f;
    bool defer = ins && (mo >= smin) && (mo < 0.7f);   // gb can only hit these
    labels[i] = lab;                                    // provisional if deferred
    unsigned bits = __float_as_uint(noise[i]);
    if (!defer) {
        if (lab == 1.0f)      { atomicAdd(&sc[S_CNT_FG], 1u); atomicAdd(&hfh[bits >> 16], 1u); }
        else if (lab == 0.0f) { atomicAdd(&sc[S_CNT_BG], 1u); atomicAdd(&hbh[bits >> 16], 1u); }
    }
    unsigned long long m = __ballot(defer);
    if (m) {
        int lane = t & 63;
        int leader = __ffsll((unsigned long long)m) - 1;
        unsigned base = 0;
        if (lane == leader) base = atomicAdd(&sc[S_WL], (unsigned)__popcll(m));
        base = __shfl(base, leader, 64);
        if (defer) {
            unsigned off = (unsigned)__popcll(m & ((1ull << lane) - 1ull));
            wl[base + off] = (unsigned)i;
        }
    }
}

// Labels pass B: resolve gt-best over compacted candidates only.
__global__ __launch_bounds__(256) void k_labels_b(
    const float4* __restrict__ anchors, const float4* __restrict__ sgtb,
    const float* __restrict__ sgab, const float* __restrict__ sgmb,
    const float* __restrict__ maxov, const float* __restrict__ noise,
    const unsigned* __restrict__ wl, float* __restrict__ labels,
    unsigned* __restrict__ hfh, unsigned* __restrict__ hbh,
    unsigned* __restrict__ sc) {
    __shared__ float4 sg[NK];
    __shared__ float  sga[NK];
    __shared__ float  sgm[NK];
    int t = threadIdx.x;
    if (t < NK) { sg[t] = sgtb[t]; sga[t] = sgab[t]; sgm[t] = sgmb[t]; }
    __syncthreads();
    unsigned cnt = sc[S_WL];
    for (unsigned j = blockIdx.x * 256 + t; j < cnt; j += gridDim.x * 256) {
        unsigned i = wl[j];
        float4 a = anchors[i];
        float mo = maxov[i];
        float ba = (a.z - a.x + 1.0f) * (a.w - a.y + 1.0f);
        bool gb = false;
        for (int q = 0; q < NK; ++q) {
            float gm = sgm[q];
            if (gm > mo) break;          // ov[i][k] <= mo < gt_max[k]: can't match
            float4 g = sg[q];
            float iw = fmaxf(fminf(a.z, g.z) - fmaxf(a.x, g.x) + 1.0f, 0.0f);
            float ih = fmaxf(fminf(a.w, g.w) - fmaxf(a.y, g.y) + 1.0f, 0.0f);
            float it = iw * ih;
            float v = it / (ba + sga[q] - it);
            gb = gb || (v == gm);        // exact equality, same rounding as pass 1
        }
        float lab = gb ? 1.0f : (mo < 0.3f ? 0.0f : -1.0f);
        if (gb) labels[i] = 1.0f;
        unsigned bits = __float_as_uint(noise[i]);
        if (lab == 1.0f)      { atomicAdd(&sc[S_CNT_FG], 1u); atomicAdd(&hfh[bits >> 16], 1u); }
        else if (lab == 0.0f) { atomicAdd(&sc[S_CNT_BG], 1u); atomicAdd(&hbh[bits >> 16], 1u); }
    }
}

// hi-16 radix select for fg
__global__ __launch_bounds__(256) void k_scan_hi_fg(
    const unsigned* __restrict__ hist, unsigned* __restrict__ sc) {
    __shared__ unsigned csum[256];
    __shared__ unsigned suf[256];
    int t = threadIdx.x;
    unsigned cnt = sc[S_CNT_FG];
    int active = cnt > 128u;
    if (t == 0) sc[S_FG_ACTIVE] = (unsigned)active;
    if (!active) return;
    const unsigned k = 128u;
    const unsigned* hp = hist + t * 256;
    unsigned s = 0;
    for (int b = 0; b < 256; ++b) s += hp[b];
    csum[t] = s;
    __syncthreads();
    if (t == 0) {
        unsigned run = 0;
        for (int c = 255; c >= 0; --c) { suf[c] = run; run += csum[c]; }
    }
    __syncthreads();
    unsigned above = suf[t];
    if (above < k && k <= above + csum[t]) {
        unsigned c = above;
        for (int b = 255; b >= 0; --b) {
            unsigned h = hp[b];
            c += h;
            if (c >= k) { sc[S_FG_BIN] = (unsigned)(t * 256 + b); sc[S_FG_REM] = k - (c - h); break; }
        }
    }
}

// lo-16 histogram restricted to the selected hi bin
__global__ __launch_bounds__(256) void k_hist_lo(
    const float* __restrict__ labels, const float* __restrict__ noise,
    const unsigned* __restrict__ sc, unsigned* __restrict__ hist, int isBg) {
    if (!sc[isBg ? S_BG_ACTIVE : S_FG_ACTIVE]) return;
    unsigned hib = sc[isBg ? S_BG_BIN : S_FG_BIN];
    int i = blockIdx.x * 256 + threadIdx.x;
    float target = isBg ? 0.0f : 1.0f;
    if (labels[i] == target) {
        unsigned bits = __float_as_uint(noise[i]);
        if ((bits >> 16) == hib) atomicAdd(&hist[bits & 0xFFFFu], 1u);
    }
}

// merged: lo-16 select for fg  ->  hi-16 select for bg
__global__ __launch_bounds__(256) void k_mid(
    const unsigned* __restrict__ hfl, const unsigned* __restrict__ hbh,
    unsigned* __restrict__ sc) {
    __shared__ unsigned csum[256];
    __shared__ unsigned suf[256];
    __shared__ unsigned snfg;
    int t = threadIdx.x;
    unsigned factive = sc[S_FG_ACTIVE];
    if (!factive) {
        if (t == 0) snfg = sc[S_CNT_FG];
    } else {
        unsigned rem = sc[S_FG_REM];
        unsigned hib = sc[S_FG_BIN];
        const unsigned* hp = hfl + t * 256;
        unsigned s = 0;
        for (int b = 0; b < 256; ++b) s += hp[b];
        csum[t] = s;
        __syncthreads();
        if (t == 0) {
            unsigned run = 0;
            for (int c = 255; c >= 0; --c) { suf[c] = run; run += csum[c]; }
        }
        __syncthreads();
        unsigned above = suf[t];
        if (above < rem && rem <= above + csum[t]) {
            unsigned c = above;
            for (int b = 255; b >= 0; --b) {
                unsigned h = hp[b];
                c += h;
                if (c >= rem) {
                    sc[S_FG_TH] = (hib << 16) | (unsigned)(t * 256 + b);
                    snfg = (128u - rem) + c;
                    break;
                }
            }
        }
    }
    __syncthreads();
    int nfg = (int)snfg;
    int num_bg = 256 - nfg;
    int cnt = (int)sc[S_CNT_BG];
    int bactive = cnt > num_bg;
    int kk = num_bg < 1 ? 1 : num_bg;
    unsigned k = (unsigned)kk;
    if (t == 0) { sc[S_BG_ACTIVE] = (unsigned)bactive; sc[S_BG_K] = k; sc[S_NFG_FINAL] = (unsigned)nfg; }
    if (!bactive) return;
    const unsigned* hp = hbh + t * 256;
    unsigned s = 0;
    for (int b = 0; b < 256; ++b) s += hp[b];
    csum[t] = s;
    __syncthreads();
    if (t == 0) {
        unsigned run = 0;
        for (int c = 255; c >= 0; --c) { suf[c] = run; run += csum[c]; }
    }
    __syncthreads();
    unsigned above = suf[t];
    if (above < k && k <= above + csum[t]) {
        unsigned c = above;
        for (int b = 255; b >= 0; --b) {
            unsigned h = hp[b];
            c += h;
            if (c >= k) { sc[S_BG_BIN] = (unsigned)(t * 256 + b); sc[S_BG_REM] = k - (c - h); break; }
        }
    }
}

// lo-16 select for bg -> threshold + S_NUM_EX
__global__ __launch_bounds__(256) void k_scan_lo_bg(
    const unsigned* __restrict__ hist, unsigned* __restrict__ sc) {
    __shared__ unsigned csum[256];
    __shared__ unsigned suf[256];
    int t = threadIdx.x;
    unsigned active = sc[S_BG_ACTIVE];
    if (!active) {
        if (t == 0) sc[S_NUM_EX] = sc[S_NFG_FINAL] + sc[S_CNT_BG];
        return;
    }
    unsigned rem   = sc[S_BG_REM];
    unsigned hib   = sc[S_BG_BIN];
    unsigned korig = sc[S_BG_K];
    const unsigned* hp = hist + t * 256;
    unsigned s = 0;
    for (int b = 0; b < 256; ++b) s += hp[b];
    csum[t] = s;
    __syncthreads();
    if (t == 0) {
        unsigned run = 0;
        for (int c = 255; c >= 0; --c) { suf[c] = run; run += csum[c]; }
    }
    __syncthreads();
    unsigned above = suf[t];
    if (above < rem && rem <= above + csum[t]) {
        unsigned c = above;
        for (int b = 255; b >= 0; --b) {
            unsigned h = hp[b];
            c += h;
            if (c >= rem) {
                sc[S_BG_TH] = (hib << 16) | (unsigned)(t * 256 + b);
                sc[S_NUM_EX] = sc[S_NFG_FINAL] + ((korig - rem) + c);
                break;
            }
        }
    }
}

// Final: apply disables, permuted label write, targets, weights
__global__ __launch_bounds__(256) void k_final(
    const float4* __restrict__ anchors, const float4* __restrict__ gt,
    const float* __restrict__ noise, const float* __restrict__ labels,
    const unsigned char* __restrict__ argm, const float* __restrict__ maxov,
    const unsigned* __restrict__ sc,
    float* __restrict__ out0, float4* __restrict__ out1,
    float4* __restrict__ out2, float4* __restrict__ out3) {
    int i = blockIdx.x * 256 + threadIdx.x;
    unsigned fga = sc[S_FG_ACTIVE], bga = sc[S_BG_ACTIVE];
    float thf = __uint_as_float(sc[S_FG_TH]);
    float thb = __uint_as_float(sc[S_BG_TH]);

    // out0: dest-indexed permuted labels. dest i = a*HW + cell; src = cell*NA + a
    {
        int a0 = i / HW_, cell0 = i % HW_;
        int src = cell0 * NA + a0;
        float lab0 = labels[src];
        float nz0 = noise[src];
        if (fga && lab0 == 1.0f && nz0 < thf) lab0 = -1.0f;
        if (bga && lab0 == 0.0f && nz0 < thb) lab0 = -1.0f;
        out0[i] = lab0;
    }

    float lab = labels[i];
    float nz = noise[i];
    if (fga && lab == 1.0f && nz < thf) lab = -1.0f;
    if (bga && lab == 0.0f && nz < thb) lab = -1.0f;

    float4 an = anchors[i];
    float4 g = gt[argm[i]];
    float ew = an.z - an.x + 1.0f, eh = an.w - an.y + 1.0f;
    float ecx = an.x + 0.5f * ew,  ecy = an.y + 0.5f * eh;
    float gw = g.z - g.x + 1.0f,   gh = g.w - g.y + 1.0f;
    float gcx = g.x + 0.5f * gw,   gcy = g.y + 0.5f * gh;
    float t0 = (gcx - ecx) / ew;
    float t1 = (gcy - ecy) / eh;
    float t2 = logf(gw / ew);
    float t3 = logf(gh / eh);
    if (maxov[i] < 0.0f) { t0 = 0.0f; t1 = 0.0f; t2 = 0.0f; t3 = 0.0f; }  // outside
    out1[i] = make_float4(t0, t1, t2, t3);

    float biw = (lab == 1.0f) ? 1.0f : 0.0f;
    out2[i] = make_float4(biw, biw, biw, biw);

    float inv = 1.0f / (float)sc[S_NUM_EX];
    float bow = (lab >= 0.0f) ? inv : 0.0f;
    out3[i] = make_float4(bow, bow, bow, bow);
}

extern "C" void kernel_launch(void* const* d_in, const int* in_sizes, int n_in,
                              void* d_out, int out_size, void* d_ws, size_t ws_size,
                              hipStream_t stream) {
    const float4* anchors = (const float4*)d_in[0];
    const float4* gt      = (const float4*)d_in[1];
    const float*  iminfo  = (const float*)d_in[2];
    const float*  noise   = (const float*)d_in[3];

    float*  out0 = (float*)d_out;                  // NN
    float4* out1 = (float4*)(out0 + NN);           // NN x 4
    float4* out2 = (float4*)(out0 + NN + 4 * NN);  // NN x 4
    float4* out3 = (float4*)(out0 + NN + 8 * NN);  // NN x 4

    char* ws = (char*)d_ws;
    unsigned* sc   = (unsigned*)ws;                         // 64 u32
    unsigned* gtm  = (unsigned*)(ws + 256);                 // 128 u32
    float*    sgmv = (float*)(ws + 768);                    // 128 f32
    float*    sgar = (float*)(ws + 1280);                   // 128 f32
    float4*   sgt  = (float4*)(ws + 1792);                  // 128 f4
    unsigned* hfh  = (unsigned*)(ws + 4096);                // 65536 u32 x4
    unsigned* hfl  = hfh + 65536;
    unsigned* hbh  = hfl + 65536;
    unsigned* hbl  = hbh + 65536;
    float* labels  = (float*)(ws + 1052672);                // NN f32
    float* maxov   = labels + NN;                           // NN f32
    unsigned char* argm = (unsigned char*)(maxov + NN);     // NN u8
    unsigned* wl   = (unsigned*)(ws + 3126272);             // NN u32 worklist

    // zero: sc + gtm + sorted + 4 histograms (4096B header + 1MB)
    k_init<<<512, 256, 0, stream>>>((unsigned*)ws, 263168);
    k_row<<<450, 256, 0, stream>>>(anchors, gt, iminfo, maxov, argm);
    k_col<<<450, 256, 0, stream>>>(anchors, gt, iminfo, gtm);
    k_sortgt<<<1, 128, 0, stream>>>(gt, gtm, sgt, sgar, sgmv, sc);
    k_labels_a<<<NBLK, 256, 0, stream>>>(maxov, noise, sc, labels, hfh, hbh, wl);
    k_labels_b<<<256, 256, 0, stream>>>(anchors, sgt, sgar, sgmv, maxov, noise, wl,
                                        labels, hfh, hbh, sc);
    k_scan_hi_fg<<<1, 256, 0, stream>>>(hfh, sc);
    k_hist_lo<<<NBLK, 256, 0, stream>>>(labels, noise, sc, hfl, 0);
    k_mid<<<1, 256, 0, stream>>>(hfl, hbh, sc);
    k_hist_lo<<<NBLK, 256, 0, stream>>>(labels, noise, sc, hbl, 1);
    k_scan_lo_bg<<<1, 256, 0, stream>>>(hbl, sc);
    k_final<<<NBLK, 256, 0, stream>>>(anchors, gt, noise, labels, argm, maxov, sc,
                                      out0, out1, out2, out3);
}

// Round 4
// 300.053 us; speedup vs baseline: 1.0594x; 1.0594x over previous
//
#include <hip/hip_runtime.h>
#include <hip/hip_bf16.h>

#pragma clang fp contract(off)

#define NN   230400   // H*W*A
#define NK   128      // gt boxes
#define HW_  25600    // H*W
#define NA   9
#define NBLK 900      // NN/256
#define CCHUNK 512    // anchors per k_col block

// ---- scalar slots in ws (sc has 128 u32; S_WL isolated on its own line) ----
enum { S_CNT_FG=0, S_CNT_BG, S_FG_ACTIVE, S_FG_BIN, S_FG_REM, S_FG_TH, S_NFG_FINAL,
       S_BG_ACTIVE, S_BG_BIN, S_BG_REM, S_BG_TH, S_BG_K, S_NUM_EX, S_SMIN };
#define S_WL 64

__device__ __forceinline__ unsigned encf(float f) {
    unsigned u = __float_as_uint(f);
    return (u & 0x80000000u) ? ~u : (u | 0x80000000u);
}
__device__ __forceinline__ float decf(unsigned e) {
    unsigned u = (e & 0x80000000u) ? (e & 0x7FFFFFFFu) : ~e;
    return __uint_as_float(u);
}
// bijective 16-bit scramble: adjacent (hot) bins land 16KB apart -> no L2 line contention
__device__ __forceinline__ unsigned hperm(unsigned b) {
    return ((b & 0xFu) << 12) | (b >> 4);
}

__global__ __launch_bounds__(256) void k_init(unsigned* __restrict__ p, int n) {
    int i = blockIdx.x * blockDim.x + threadIdx.x;
    for (; i < n; i += gridDim.x * blockDim.x) p[i] = 0u;
}

// Row pass: thread = anchor (x2), loop over 128 gts in LDS. No shuffles, no atomics.
__global__ __launch_bounds__(256) void k_row(
    const float4* __restrict__ anchors, const float4* __restrict__ gt,
    const float* __restrict__ iminfo, float* __restrict__ maxov,
    unsigned char* __restrict__ argm) {
    __shared__ float4 sg[NK];
    __shared__ float  sga[NK];
    int t = threadIdx.x;
    if (t < NK) {
        float4 g = gt[t];
        sg[t] = g;
        sga[t] = (g.z - g.x + 1.0f) * (g.w - g.y + 1.0f);
    }
    __syncthreads();
    int i0 = blockIdx.x * 512 + t, i1 = i0 + 256;
    float4 a0 = anchors[i0], a1 = anchors[i1];
    float imh = iminfo[0], imw = iminfo[1];
    bool in0 = (a0.x >= 0.0f) && (a0.y >= 0.0f) && (a0.z < imw) && (a0.w < imh);
    bool in1 = (a1.x >= 0.0f) && (a1.y >= 0.0f) && (a1.z < imw) && (a1.w < imh);
    float ba0 = (a0.z - a0.x + 1.0f) * (a0.w - a0.y + 1.0f);
    float ba1 = (a1.z - a1.x + 1.0f) * (a1.w - a1.y + 1.0f);
    float b0 = -INFINITY, b1 = -INFINITY;
    int x0 = 0, x1 = 0;
    for (int k = 0; k < NK; ++k) {
        float4 g = sg[k];
        float ga = sga[k];
        float iw0 = fmaxf(fminf(a0.z, g.z) - fmaxf(a0.x, g.x) + 1.0f, 0.0f);
        float ih0 = fmaxf(fminf(a0.w, g.w) - fmaxf(a0.y, g.y) + 1.0f, 0.0f);
        float it0 = iw0 * ih0;
        float v0 = it0 / (ba0 + ga - it0);
        float ov0 = in0 ? v0 : -1.0f;
        if (ov0 > b0) { b0 = ov0; x0 = k; }       // strict > => first max (jnp.argmax)
        float iw1 = fmaxf(fminf(a1.z, g.z) - fmaxf(a1.x, g.x) + 1.0f, 0.0f);
        float ih1 = fmaxf(fminf(a1.w, g.w) - fmaxf(a1.y, g.y) + 1.0f, 0.0f);
        float it1 = iw1 * ih1;
        float v1 = it1 / (ba1 + ga - it1);
        float ov1 = in1 ? v1 : -1.0f;
        if (ov1 > b1) { b1 = ov1; x1 = k; }
    }
    maxov[i0] = b0; argm[i0] = (unsigned char)x0;   // inside <=> maxov >= 0
    maxov[i1] = b1; argm[i1] = (unsigned char)x1;
}

// Column pass: thread = gt column (k = t&127, anchor-half = t>>7). No shuffles.
__global__ __launch_bounds__(256) void k_col(
    const float4* __restrict__ anchors, const float4* __restrict__ gt,
    const float* __restrict__ iminfo, unsigned* __restrict__ gtm) {
    __shared__ float4 sa[CCHUNK];
    __shared__ float  sba[CCHUNK];       // ba, or -1 flag if outside
    __shared__ float  sm[2][NK];
    int t = threadIdx.x;
    int k = t & 127, h = t >> 7;
    float4 g = gt[k];
    float ga = (g.z - g.x + 1.0f) * (g.w - g.y + 1.0f);
    float imh = iminfo[0], imw = iminfo[1];
    int base = blockIdx.x * CCHUNK;
    for (int j = t; j < CCHUNK; j += 256) {
        float4 a = anchors[base + j];
        sa[j] = a;
        bool ins = (a.x >= 0.0f) && (a.y >= 0.0f) && (a.z < imw) && (a.w < imh);
        float ba = (a.z - a.x + 1.0f) * (a.w - a.y + 1.0f);
        sba[j] = ins ? ba : -1.0f;       // outside anchors never set a column max
    }
    __syncthreads();
    float run = -1.0f;
    int j0 = h * 256;
    for (int j = 0; j < 256; ++j) {
        float4 a = sa[j0 + j];           // same addr across lanes -> LDS broadcast
        float ba = sba[j0 + j];
        float iw = fmaxf(fminf(a.z, g.z) - fmaxf(a.x, g.x) + 1.0f, 0.0f);
        float ih = fmaxf(fminf(a.w, g.w) - fmaxf(a.y, g.y) + 1.0f, 0.0f);
        float it = iw * ih;
        float v = it / (ba + ga - it);
        float ov = (ba < 0.0f) ? -1.0f : v;
        run = fmaxf(run, ov);
    }
    sm[h][k] = run;
    __syncthreads();
    if (t < NK) {
        unsigned e = encf(fmaxf(sm[0][t], sm[1][t]));
        if (e > gtm[t]) atomicMax(&gtm[t], e);   // racy prefilter; atomic authoritative
    }
}

// Sort columns ascending by gt_max (ties by index) + publish smin. 1 block.
__global__ __launch_bounds__(128) void k_sortgt(
    const float4* __restrict__ gt, const unsigned* __restrict__ gtm,
    float4* __restrict__ sgt, float* __restrict__ sgar, float* __restrict__ sgmv,
    unsigned* __restrict__ sc) {
    __shared__ unsigned se[NK];
    int t = threadIdx.x;
    unsigned e = gtm[t];
    se[t] = e;
    __syncthreads();
    int rank = 0;
    for (int j = 0; j < NK; ++j) {
        unsigned ej = se[j];
        rank += (ej < e) || (ej == e && j < t);
    }
    float4 g = gt[t];
    float val = decf(e);
    sgt[rank]  = g;
    sgar[rank] = (g.z - g.x + 1.0f) * (g.w - g.y + 1.0f);
    sgmv[rank] = val;
    if (rank == 0) sc[S_SMIN] = __float_as_uint(val);
}

// Labels pass A: loop-free. NO count atomics (counts derived from hist totals).
// Histogram atomics at hperm'd addresses (spread). Candidates -> worklist.
__global__ __launch_bounds__(256) void k_labels_a(
    const float* __restrict__ maxov, const float* __restrict__ noise,
    unsigned* __restrict__ sc, float* __restrict__ labels,
    unsigned* __restrict__ hfh, unsigned* __restrict__ hbh,
    unsigned* __restrict__ wl) {
    int t = threadIdx.x;
    int i = blockIdx.x * 256 + t;
    float mo = maxov[i];
    bool ins = mo >= 0.0f;
    float smin = __uint_as_float(sc[S_SMIN]);
    float lab = -1.0f;
    if (ins && mo < 0.3f)  lab = 0.0f;
    if (ins && mo >= 0.7f) lab = 1.0f;
    bool defer = ins && (mo >= smin) && (mo < 0.7f);   // gb can only hit these
    labels[i] = lab;                                    // provisional if deferred
    unsigned bits = __float_as_uint(noise[i]);
    if (!defer) {
        if (lab == 1.0f)      atomicAdd(&hfh[hperm(bits >> 16)], 1u);
        else if (lab == 0.0f) atomicAdd(&hbh[hperm(bits >> 16)], 1u);
    }
    unsigned long long m = __ballot(defer);
    if (m) {
        int lane = t & 63;
        int leader = __ffsll((unsigned long long)m) - 1;
        unsigned base = 0;
        if (lane == leader) base = atomicAdd(&sc[S_WL], (unsigned)__popcll(m));
        base = __shfl(base, leader, 64);
        if (defer) {
            unsigned off = (unsigned)__popcll(m & ((1ull << lane) - 1ull));
            wl[base + off] = (unsigned)i;
        }
    }
}

// Labels pass B: resolve gt-best over compacted candidates only.
__global__ __launch_bounds__(256) void k_labels_b(
    const float4* __restrict__ anchors, const float4* __restrict__ sgtb,
    const float* __restrict__ sgab, const float* __restrict__ sgmb,
    const float* __restrict__ maxov, const float* __restrict__ noise,
    const unsigned* __restrict__ wl, float* __restrict__ labels,
    unsigned* __restrict__ hfh, unsigned* __restrict__ hbh,
    unsigned* __restrict__ sc) {
    __shared__ float4 sg[NK];
    __shared__ float  sga[NK];
    __shared__ float  sgm[NK];
    int t = threadIdx.x;
    if (t < NK) { sg[t] = sgtb[t]; sga[t] = sgab[t]; sgm[t] = sgmb[t]; }
    __syncthreads();
    unsigned cnt = sc[S_WL];
    for (unsigned j = blockIdx.x * 256 + t; j < cnt; j += gridDim.x * 256) {
        unsigned i = wl[j];
        float4 a = anchors[i];
        float mo = maxov[i];
        float ba = (a.z - a.x + 1.0f) * (a.w - a.y + 1.0f);
        bool gb = false;
        for (int q = 0; q < NK; ++q) {
            float gm = sgm[q];
            if (gm > mo) break;          // ov[i][k] <= mo < gt_max[k]: can't match
            float4 g = sg[q];
            float iw = fmaxf(fminf(a.z, g.z) - fmaxf(a.x, g.x) + 1.0f, 0.0f);
            float ih = fmaxf(fminf(a.w, g.w) - fmaxf(a.y, g.y) + 1.0f, 0.0f);
            float it = iw * ih;
            float v = it / (ba + sga[q] - it);
            gb = gb || (v == gm);        // exact equality, same rounding as pass 1
        }
        float lab = gb ? 1.0f : (mo < 0.3f ? 0.0f : -1.0f);
        if (gb) labels[i] = 1.0f;
        unsigned bits = __float_as_uint(noise[i]);
        if (lab == 1.0f)      atomicAdd(&hfh[hperm(bits >> 16)], 1u);
        else if (lab == 0.0f) atomicAdd(&hbh[hperm(bits >> 16)], 1u);
    }
}

// hi-16 radix select for fg (perm reads). Also derives cnt_fg = hist total.
__global__ __launch_bounds__(256) void k_scan_hi_fg(
    const unsigned* __restrict__ hist, unsigned* __restrict__ sc) {
    __shared__ unsigned csum[256];
    __shared__ unsigned suf[256];
    __shared__ unsigned stot;
    int t = threadIdx.x;
    unsigned s = 0;
    for (int b = 0; b < 256; ++b) s += hist[hperm((unsigned)(t * 256 + b))];
    csum[t] = s;
    __syncthreads();
    if (t == 0) {
        unsigned run = 0;
        for (int c = 255; c >= 0; --c) { suf[c] = run; run += csum[c]; }
        stot = run;
    }
    __syncthreads();
    unsigned cnt = stot;
    int active = cnt > 128u;
    if (t == 0) { sc[S_FG_ACTIVE] = (unsigned)active; sc[S_CNT_FG] = cnt; }
    if (!active) return;
    const unsigned k = 128u;
    unsigned above = suf[t];
    if (above < k && k <= above + csum[t]) {
        unsigned c = above;
        for (int b = 255; b >= 0; --b) {
            unsigned h = hist[hperm((unsigned)(t * 256 + b))];
            c += h;
            if (c >= k) { sc[S_FG_BIN] = (unsigned)(t * 256 + b); sc[S_FG_REM] = k - (c - h); break; }
        }
    }
}

// lo-16 histogram restricted to the selected hi bin (identity layout: uniform bins)
__global__ __launch_bounds__(256) void k_hist_lo(
    const float* __restrict__ labels, const float* __restrict__ noise,
    const unsigned* __restrict__ sc, unsigned* __restrict__ hist, int isBg) {
    if (!sc[isBg ? S_BG_ACTIVE : S_FG_ACTIVE]) return;
    unsigned hib = sc[isBg ? S_BG_BIN : S_FG_BIN];
    int i = blockIdx.x * 256 + threadIdx.x;
    float target = isBg ? 0.0f : 1.0f;
    if (labels[i] == target) {
        unsigned bits = __float_as_uint(noise[i]);
        if ((bits >> 16) == hib) atomicAdd(&hist[bits & 0xFFFFu], 1u);
    }
}

// merged: lo-16 select for fg -> hi-16 select for bg (cnt_bg from hbh total)
__global__ __launch_bounds__(256) void k_mid(
    const unsigned* __restrict__ hfl, const unsigned* __restrict__ hbh,
    unsigned* __restrict__ sc) {
    __shared__ unsigned csum[256];
    __shared__ unsigned suf[256];
    __shared__ unsigned snfg;
    __shared__ unsigned stot;
    int t = threadIdx.x;
    unsigned factive = sc[S_FG_ACTIVE];
    if (!factive) {
        if (t == 0) snfg = sc[S_CNT_FG];
    } else {
        unsigned rem = sc[S_FG_REM];
        unsigned hib = sc[S_FG_BIN];
        const unsigned* hp = hfl + t * 256;
        unsigned s = 0;
        for (int b = 0; b < 256; ++b) s += hp[b];
        csum[t] = s;
        __syncthreads();
        if (t == 0) {
            unsigned run = 0;
            for (int c = 255; c >= 0; --c) { suf[c] = run; run += csum[c]; }
        }
        __syncthreads();
        unsigned above = suf[t];
        if (above < rem && rem <= above + csum[t]) {
            unsigned c = above;
            for (int b = 255; b >= 0; --b) {
                unsigned h = hp[b];
                c += h;
                if (c >= rem) {
                    sc[S_FG_TH] = (hib << 16) | (unsigned)(t * 256 + b);
                    snfg = (128u - rem) + c;
                    break;
                }
            }
        }
    }
    __syncthreads();
    int nfg = (int)snfg;
    int num_bg = 256 - nfg;
    // ---- bg hi-16 select (perm reads) ----
    unsigned s = 0;
    for (int b = 0; b < 256; ++b) s += hbh[hperm((unsigned)(t * 256 + b))];
    __syncthreads();                      // csum/suf reuse barrier
    csum[t] = s;
    __syncthreads();
    if (t == 0) {
        unsigned run = 0;
        for (int c = 255; c >= 0; --c) { suf[c] = run; run += csum[c]; }
        stot = run;
    }
    __syncthreads();
    int cnt = (int)stot;
    int bactive = cnt > num_bg;
    int kk = num_bg < 1 ? 1 : num_bg;
    unsigned k = (unsigned)kk;
    if (t == 0) {
        sc[S_BG_ACTIVE] = (unsigned)bactive; sc[S_BG_K] = k;
        sc[S_NFG_FINAL] = (unsigned)nfg;    sc[S_CNT_BG] = (unsigned)cnt;
    }
    if (!bactive) return;
    unsigned above = suf[t];
    if (above < k && k <= above + csum[t]) {
        unsigned c = above;
        for (int b = 255; b >= 0; --b) {
            unsigned h = hbh[hperm((unsigned)(t * 256 + b))];
            c += h;
            if (c >= k) { sc[S_BG_BIN] = (unsigned)(t * 256 + b); sc[S_BG_REM] = k - (c - h); break; }
        }
    }
}

// lo-16 select for bg -> threshold + S_NUM_EX
__global__ __launch_bounds__(256) void k_scan_lo_bg(
    const unsigned* __restrict__ hist, unsigned* __restrict__ sc) {
    __shared__ unsigned csum[256];
    __shared__ unsigned suf[256];
    int t = threadIdx.x;
    unsigned active = sc[S_BG_ACTIVE];
    if (!active) {
        if (t == 0) sc[S_NUM_EX] = sc[S_NFG_FINAL] + sc[S_CNT_BG];
        return;
    }
    unsigned rem   = sc[S_BG_REM];
    unsigned hib   = sc[S_BG_BIN];
    unsigned korig = sc[S_BG_K];
    const unsigned* hp = hist + t * 256;
    unsigned s = 0;
    for (int b = 0; b < 256; ++b) s += hp[b];
    csum[t] = s;
    __syncthreads();
    if (t == 0) {
        unsigned run = 0;
        for (int c = 255; c >= 0; --c) { suf[c] = run; run += csum[c]; }
    }
    __syncthreads();
    unsigned above = suf[t];
    if (above < rem && rem <= above + csum[t]) {
        unsigned c = above;
        for (int b = 255; b >= 0; --b) {
            unsigned h = hp[b];
            c += h;
            if (c >= rem) {
                sc[S_BG_TH] = (hib << 16) | (unsigned)(t * 256 + b);
                sc[S_NUM_EX] = sc[S_NFG_FINAL] + ((korig - rem) + c);
                break;
            }
        }
    }
}

// Final: apply disables, permuted label write, targets, weights
__global__ __launch_bounds__(256) void k_final(
    const float4* __restrict__ anchors, const float4* __restrict__ gt,
    const float* __restrict__ noise, const float* __restrict__ labels,
    const unsigned char* __restrict__ argm, const float* __restrict__ maxov,
    const unsigned* __restrict__ sc,
    float* __restrict__ out0, float4* __restrict__ out1,
    float4* __restrict__ out2, float4* __restrict__ out3) {
    int i = blockIdx.x * 256 + threadIdx.x;
    unsigned fga = sc[S_FG_ACTIVE], bga = sc[S_BG_ACTIVE];
    float thf = __uint_as_float(sc[S_FG_TH]);
    float thb = __uint_as_float(sc[S_BG_TH]);

    // out0: dest-indexed permuted labels. dest i = a*HW + cell; src = cell*NA + a
    {
        int a0 = i / HW_, cell0 = i % HW_;
        int src = cell0 * NA + a0;
        float lab0 = labels[src];
        float nz0 = noise[src];
        if (fga && lab0 == 1.0f && nz0 < thf) lab0 = -1.0f;
        if (bga && lab0 == 0.0f && nz0 < thb) lab0 = -1.0f;
        out0[i] = lab0;
    }

    float lab = labels[i];
    float nz = noise[i];
    if (fga && lab == 1.0f && nz < thf) lab = -1.0f;
    if (bga && lab == 0.0f && nz < thb) lab = -1.0f;

    float4 an = anchors[i];
    float4 g = gt[argm[i]];
    float ew = an.z - an.x + 1.0f, eh = an.w - an.y + 1.0f;
    float ecx = an.x + 0.5f * ew,  ecy = an.y + 0.5f * eh;
    float gw = g.z - g.x + 1.0f,   gh = g.w - g.y + 1.0f;
    float gcx = g.x + 0.5f * gw,   gcy = g.y + 0.5f * gh;
    float t0 = (gcx - ecx) / ew;
    float t1 = (gcy - ecy) / eh;
    float t2 = logf(gw / ew);
    float t3 = logf(gh / eh);
    if (maxov[i] < 0.0f) { t0 = 0.0f; t1 = 0.0f; t2 = 0.0f; t3 = 0.0f; }  // outside
    out1[i] = make_float4(t0, t1, t2, t3);

    float biw = (lab == 1.0f) ? 1.0f : 0.0f;
    out2[i] = make_float4(biw, biw, biw, biw);

    float inv = 1.0f / (float)sc[S_NUM_EX];
    float bow = (lab >= 0.0f) ? inv : 0.0f;
    out3[i] = make_float4(bow, bow, bow, bow);
}

extern "C" void kernel_launch(void* const* d_in, const int* in_sizes, int n_in,
                              void* d_out, int out_size, void* d_ws, size_t ws_size,
                              hipStream_t stream) {
    const float4* anchors = (const float4*)d_in[0];
    const float4* gt      = (const float4*)d_in[1];
    const float*  iminfo  = (const float*)d_in[2];
    const float*  noise   = (const float*)d_in[3];

    float*  out0 = (float*)d_out;                  // NN
    float4* out1 = (float4*)(out0 + NN);           // NN x 4
    float4* out2 = (float4*)(out0 + NN + 4 * NN);  // NN x 4
    float4* out3 = (float4*)(out0 + NN + 8 * NN);  // NN x 4

    char* ws = (char*)d_ws;
    unsigned* sc   = (unsigned*)ws;                         // 128 u32 (S_WL @ +256B)
    unsigned* gtm  = (unsigned*)(ws + 512);                 // 128 u32
    float*    sgmv = (float*)(ws + 1024);                   // 128 f32
    float*    sgar = (float*)(ws + 1536);                   // 128 f32
    float4*   sgt  = (float4*)(ws + 2048);                  // 128 f4 -> ends 4096
    unsigned* hfh  = (unsigned*)(ws + 4096);                // 65536 u32 x4
    unsigned* hfl  = hfh + 65536;
    unsigned* hbh  = hfl + 65536;
    unsigned* hbl  = hbh + 65536;
    float* labels  = (float*)(ws + 1052672);                // NN f32
    float* maxov   = labels + NN;                           // NN f32
    unsigned char* argm = (unsigned char*)(maxov + NN);     // NN u8
    unsigned* wl   = (unsigned*)(ws + 3126272);             // NN u32 worklist

    // zero: sc + gtm + sorted + 4 histograms (4096B header + 1MB)
    k_init<<<512, 256, 0, stream>>>((unsigned*)ws, 263168);
    k_row<<<450, 256, 0, stream>>>(anchors, gt, iminfo, maxov, argm);
    k_col<<<450, 256, 0, stream>>>(anchors, gt, iminfo, gtm);
    k_sortgt<<<1, 128, 0, stream>>>(gt, gtm, sgt, sgar, sgmv, sc);
    k_labels_a<<<NBLK, 256, 0, stream>>>(maxov, noise, sc, labels, hfh, hbh, wl);
    k_labels_b<<<256, 256, 0, stream>>>(anchors, sgt, sgar, sgmv, maxov, noise, wl,
                                        labels, hfh, hbh, sc);
    k_scan_hi_fg<<<1, 256, 0, stream>>>(hfh, sc);
    k_hist_lo<<<NBLK, 256, 0, stream>>>(labels, noise, sc, hfl, 0);
    k_mid<<<1, 256, 0, stream>>>(hfl, hbh, sc);
    k_hist_lo<<<NBLK, 256, 0, stream>>>(labels, noise, sc, hbl, 1);
    k_scan_lo_bg<<<1, 256, 0, stream>>>(hbl, sc);
    k_final<<<NBLK, 256, 0, stream>>>(anchors, gt, noise, labels, argm, maxov, sc,
                                      out0, out1, out2, out3);
}

// Round 5
// 140.247 us; speedup vs baseline: 2.2665x; 2.1395x over previous
//
#include <hip/hip_runtime.h>
#include <hip/hip_bf16.h>

#pragma clang fp contract(off)

#define NN   230400   // H*W*A
#define NK   128      // gt boxes
#define HW_  25600    // H*W
#define NA   9
#define NBLK 900      // NN/256
#define BINS 8192
#define BCAP 64

// ---- scalar slots in ws (sc has 128 u32; S_WL isolated on its own cacheline) ----
enum { S_FG_ACTIVE=0, S_FG_TH, S_NFG_FINAL, S_BG_ACTIVE, S_BG_TH, S_NUM_EX, S_SMIN };
#define S_WL 64

__device__ __forceinline__ unsigned encf(float f) {
    unsigned u = __float_as_uint(f);
    return (u & 0x80000000u) ? ~u : (u | 0x80000000u);
}
__device__ __forceinline__ float decf(unsigned e) {
    unsigned u = (e & 0x80000000u) ? (e & 0x7FFFFFFFu) : ~e;
    return __uint_as_float(u);
}
// The ONE IoU expression (identical rounding at every use site; contract off).
__device__ __forceinline__ void iou_parts(float4 a, float ba, float4 g, float ga,
                                          float& I, float& D) {
    float iw = fmaxf(fminf(a.z, g.z) - fmaxf(a.x, g.x) + 1.0f, 0.0f);
    float ih = fmaxf(fminf(a.w, g.w) - fmaxf(a.y, g.y) + 1.0f, 0.0f);
    I = iw * ih;
    D = ba + ga - I;          // (ba+ga)-I, same assoc everywhere
}
__device__ __forceinline__ unsigned vbin(float nz) {
    unsigned b = (unsigned)(nz * 8192.0f);
    return b > 8191u ? 8191u : b;
}

__global__ __launch_bounds__(256) void k_init(unsigned* __restrict__ p, int n) {
    int i = blockIdx.x * blockDim.x + threadIdx.x;
    for (; i < n; i += gridDim.x * blockDim.x) p[i] = 0u;
}

// Fused row(max/argmax) + col(per-gt max) pass. Cross-mult trigger avoids most divs.
__global__ __launch_bounds__(256) void k_rowcol(
    const float4* __restrict__ anchors, const float4* __restrict__ gt,
    const float* __restrict__ iminfo, float* __restrict__ maxov,
    unsigned char* __restrict__ argm, unsigned* __restrict__ gtm) {
    __shared__ float4 sg[NK];
    __shared__ float  sga[NK];
    __shared__ float4 sa[256];
    __shared__ float  sba[256];          // ba, or -1 if outside
    __shared__ float  sm[2][NK];
    int t = threadIdx.x;
    if (t < NK) {
        float4 g = gt[t];
        sg[t] = g;
        sga[t] = (g.z - g.x + 1.0f) * (g.w - g.y + 1.0f);
    }
    int i = blockIdx.x * 256 + t;
    float4 a = anchors[i];
    float imh = iminfo[0], imw = iminfo[1];
    bool ins = (a.x >= 0.0f) && (a.y >= 0.0f) && (a.z < imw) && (a.w < imh);
    float ba = (a.z - a.x + 1.0f) * (a.w - a.y + 1.0f);
    sa[t] = a;
    sba[t] = ins ? ba : -1.0f;
    __syncthreads();
    // ---- phase A: row max/argmax (outside lanes: best=+inf never triggers) ----
    float best = ins ? -1.0f : INFINITY;
    int idx = 0;
    for (int k = 0; k < NK; ++k) {
        float I, D; iou_parts(a, ba, sg[k], sga[k], I, D);
        float m = best * D;
        // conservative: v^f32 > best  =>  I > best*D (rational) => passes this test
        if (I > 0.0f && I >= m - 5e-7f * m) {
            float v = I / D;                       // exact IEEE, matches labels_b
            if (v > best) { best = v; idx = k; }   // strict > = first max (jnp.argmax)
        }
    }
    if (!ins) { best = -1.0f; idx = 0; }
    else if (best < 0.0f) best = 0.0f;             // all-zero-IoU inside anchor
    maxov[i] = best;
    argm[i] = (unsigned char)idx;
    // ---- phase B: column max (thread = (gt k, anchor-half h)) ----
    int k = t & 127, h = t >> 7;
    float4 g = sg[k];
    float ga = sga[k];
    float cb = 0.0f;                               // inside anchors exist => col max >= 0
    int j0 = h * 128;
    for (int j = 0; j < 128; ++j) {
        float4 aj = sa[j0 + j];                    // same addr across lanes -> broadcast
        float baj = sba[j0 + j];
        float I, D; iou_parts(aj, baj, g, ga, I, D);
        float m = cb * D;
        if (baj >= 0.0f && I > 0.0f && I >= m - 5e-7f * m) {
            float v = I / D;
            if (v > cb) cb = v;
        }
    }
    sm[h][k] = cb;
    __syncthreads();
    if (t < NK) {
        unsigned e = encf(fmaxf(sm[0][t], sm[1][t]));
        if (e > gtm[t]) atomicMax(&gtm[t], e);     // racy prefilter; atomic authoritative
    }
}

// Sort columns ascending by gt_max (ties by index) + publish smin. 1 block.
__global__ __launch_bounds__(128) void k_sortgt(
    const float4* __restrict__ gt, const unsigned* __restrict__ gtm,
    float4* __restrict__ sgt, float* __restrict__ sgar, float* __restrict__ sgmv,
    unsigned* __restrict__ sc) {
    __shared__ unsigned se[NK];
    int t = threadIdx.x;
    unsigned e = gtm[t];
    se[t] = e;
    __syncthreads();
    int rank = 0;
    for (int j = 0; j < NK; ++j) {
        unsigned ej = se[j];
        rank += (ej < e) || (ej == e && j < t);
    }
    float4 g = gt[t];
    float val = decf(e);
    sgt[rank]  = g;
    sgar[rank] = (g.z - g.x + 1.0f) * (g.w - g.y + 1.0f);
    sgmv[rank] = val;
    if (rank == 0) sc[S_SMIN] = __float_as_uint(val);
}

// Labels A: loop-free. Value-binned hist+bucket (uniform -> no contention).
// Deferred candidates (smin <= mo < 0.7) -> worklist.
__global__ __launch_bounds__(256) void k_labels_a(
    const float* __restrict__ maxov, const float* __restrict__ noise,
    unsigned* __restrict__ sc, float* __restrict__ labels,
    unsigned* __restrict__ hfv, unsigned* __restrict__ hbv,
    float* __restrict__ bfv, float* __restrict__ bbv,
    unsigned* __restrict__ wl) {
    int t = threadIdx.x;
    int i = blockIdx.x * 256 + t;
    float mo = maxov[i];
    bool ins = mo >= 0.0f;
    float smin = __uint_as_float(sc[S_SMIN]);
    float lab = -1.0f;
    if (ins && mo < 0.3f)  lab = 0.0f;
    if (ins && mo >= 0.7f) lab = 1.0f;
    bool defer = ins && (mo >= smin) && (mo < 0.7f);
    labels[i] = lab;                                // provisional if deferred
    float nz = noise[i];
    if (!defer) {
        if (lab == 1.0f) {
            unsigned b = vbin(nz);
            unsigned s = atomicAdd(&hfv[b], 1u);
            if (s < BCAP) bfv[b * BCAP + s] = nz;
        } else if (lab == 0.0f) {
            unsigned b = vbin(nz);
            unsigned s = atomicAdd(&hbv[b], 1u);
            if (s < BCAP) bbv[b * BCAP + s] = nz;
        }
    }
    unsigned long long m = __ballot(defer);
    if (m) {
        int lane = t & 63;
        int leader = __ffsll((unsigned long long)m) - 1;
        unsigned base = 0;
        if (lane == leader) base = atomicAdd(&sc[S_WL], (unsigned)__popcll(m));
        base = __shfl(base, leader, 64);
        if (defer) {
            unsigned off = (unsigned)__popcll(m & ((1ull << lane) - 1ull));
            wl[base + off] = (unsigned)i;
        }
    }
}

// Labels B: resolve gt-best over compacted candidates only (sorted-prune loop).
__global__ __launch_bounds__(256) void k_labels_b(
    const float4* __restrict__ anchors, const float4* __restrict__ sgtb,
    const float* __restrict__ sgab, const float* __restrict__ sgmb,
    const float* __restrict__ maxov, const float* __restrict__ noise,
    const unsigned* __restrict__ wl, float* __restrict__ labels,
    unsigned* __restrict__ hfv, unsigned* __restrict__ hbv,
    float* __restrict__ bfv, float* __restrict__ bbv,
    unsigned* __restrict__ sc) {
    __shared__ float4 sg[NK];
    __shared__ float  sga[NK];
    __shared__ float  sgm[NK];
    int t = threadIdx.x;
    if (t < NK) { sg[t] = sgtb[t]; sga[t] = sgab[t]; sgm[t] = sgmb[t]; }
    __syncthreads();
    unsigned cnt = sc[S_WL];
    for (unsigned j = blockIdx.x * 256 + t; j < cnt; j += gridDim.x * 256) {
        unsigned i = wl[j];
        float4 a = anchors[i];
        float mo = maxov[i];
        float ba = (a.z - a.x + 1.0f) * (a.w - a.y + 1.0f);
        bool gb = false;
        for (int q = 0; q < NK; ++q) {
            float gm = sgm[q];
            if (gm > mo) break;           // ov <= mo < gt_max[q]: can't match
            float I, D; iou_parts(a, ba, sg[q], sga[q], I, D);
            float v = I / D;              // bit-identical to k_rowcol winner
            gb = gb || (v == gm);
        }
        float lab = gb ? 1.0f : (mo < 0.3f ? 0.0f : -1.0f);
        if (gb) labels[i] = 1.0f;
        float nz = noise[i];
        if (lab == 1.0f) {
            unsigned b = vbin(nz);
            unsigned s = atomicAdd(&hfv[b], 1u);
            if (s < BCAP) bfv[b * BCAP + s] = nz;
        } else if (lab == 0.0f) {
            unsigned b = vbin(nz);
            unsigned s = atomicAdd(&hbv[b], 1u);
            if (s < BCAP) bbv[b * BCAP + s] = nz;
        }
    }
}

// Selection: linear 8192-bin scan -> bin+rem -> exact rank-select among <=64 values.
__global__ __launch_bounds__(256) void k_sel(
    const unsigned* __restrict__ hist, const float* __restrict__ bucket,
    unsigned* __restrict__ sc, int isBg) {
    __shared__ int csum[256];
    __shared__ int suf[256];
    __shared__ int sbstar, srem, stot;
    __shared__ float sv[BCAP];
    int t = threadIdx.x;
    const unsigned* hp = hist + t * 32;
    int s = 0;
    for (int b = 0; b < 32; ++b) s += (int)hp[b];
    csum[t] = s;
    if (t == 0) { sbstar = 0; srem = 1; }
    __syncthreads();
    if (t == 0) {
        int run = 0;
        for (int c = 255; c >= 0; --c) { suf[c] = run; run += csum[c]; }
        stot = run;
    }
    __syncthreads();
    int total = stot;
    int k, active;
    if (isBg) {
        int nfg = (int)sc[S_NFG_FINAL];
        int nb = 256 - nfg;
        active = total > nb;
        k = nb < 1 ? 1 : nb;
    } else {
        active = total > 128;
        k = 128;
    }
    if (!active) {
        if (t == 0) {
            if (isBg) { sc[S_BG_ACTIVE] = 0u; sc[S_NUM_EX] = sc[S_NFG_FINAL] + (unsigned)total; }
            else      { sc[S_FG_ACTIVE] = 0u; sc[S_NFG_FINAL] = (unsigned)total; }
        }
        return;
    }
    int above = suf[t];
    if (above < k && k <= above + csum[t]) {
        int c = above;
        for (int b = 31; b >= 0; --b) {          // high bin -> low within thread range
            int h = (int)hp[b];
            c += h;
            if (c >= k) { sbstar = t * 32 + b; srem = k - (c - h); break; }
        }
    }
    __syncthreads();
    int bstar = sbstar, rem = srem;
    int cnt = (int)hist[bstar];
    if (cnt > BCAP) cnt = BCAP;
    if (t < BCAP) sv[t] = (t < cnt) ? bucket[bstar * BCAP + t] : -INFINITY;
    __syncthreads();
    if (t < cnt) {
        float v = sv[t];
        int a = 0, b2 = 0;
        for (int q = 0; q < cnt; ++q) { float u = sv[q]; a += (u > v); b2 += (u == v); }
        if (a < rem && rem <= a + b2) {          // v is the k-th largest (tie-exact)
            unsigned nk = (unsigned)(k - rem + a + b2);   // count(score >= th) in mask
            if (isBg) { sc[S_BG_TH] = __float_as_uint(v); sc[S_BG_ACTIVE] = 1u;
                        sc[S_NUM_EX] = sc[S_NFG_FINAL] + nk; }
            else      { sc[S_FG_TH] = __float_as_uint(v); sc[S_FG_ACTIVE] = 1u;
                        sc[S_NFG_FINAL] = nk; }
        }
    }
}

// Final: apply disables, permuted label write, targets, weights
__global__ __launch_bounds__(256) void k_final(
    const float4* __restrict__ anchors, const float4* __restrict__ gt,
    const float* __restrict__ noise, const float* __restrict__ labels,
    const unsigned char* __restrict__ argm, const float* __restrict__ maxov,
    const unsigned* __restrict__ sc,
    float* __restrict__ out0, float4* __restrict__ out1,
    float4* __restrict__ out2, float4* __restrict__ out3) {
    int i = blockIdx.x * 256 + threadIdx.x;
    unsigned fga = sc[S_FG_ACTIVE], bga = sc[S_BG_ACTIVE];
    float thf = __uint_as_float(sc[S_FG_TH]);
    float thb = __uint_as_float(sc[S_BG_TH]);

    // out0: dest-indexed permuted labels. dest i = a*HW + cell; src = cell*NA + a
    {
        int a0 = i / HW_, cell0 = i % HW_;
        int src = cell0 * NA + a0;
        float lab0 = labels[src];
        float nz0 = noise[src];
        if (fga && lab0 == 1.0f && nz0 < thf) lab0 = -1.0f;
        if (bga && lab0 == 0.0f && nz0 < thb) lab0 = -1.0f;
        out0[i] = lab0;
    }

    float lab = labels[i];
    float nz = noise[i];
    if (fga && lab == 1.0f && nz < thf) lab = -1.0f;
    if (bga && lab == 0.0f && nz < thb) lab = -1.0f;

    float4 an = anchors[i];
    float4 g = gt[argm[i]];
    float ew = an.z - an.x + 1.0f, eh = an.w - an.y + 1.0f;
    float ecx = an.x + 0.5f * ew,  ecy = an.y + 0.5f * eh;
    float gw = g.z - g.x + 1.0f,   gh = g.w - g.y + 1.0f;
    float gcx = g.x + 0.5f * gw,   gcy = g.y + 0.5f * gh;
    float t0 = (gcx - ecx) / ew;
    float t1 = (gcy - ecy) / eh;
    float t2 = logf(gw / ew);
    float t3 = logf(gh / eh);
    if (maxov[i] < 0.0f) { t0 = 0.0f; t1 = 0.0f; t2 = 0.0f; t3 = 0.0f; }  // outside
    out1[i] = make_float4(t0, t1, t2, t3);

    float biw = (lab == 1.0f) ? 1.0f : 0.0f;
    out2[i] = make_float4(biw, biw, biw, biw);

    float inv = 1.0f / (float)sc[S_NUM_EX];
    float bow = (lab >= 0.0f) ? inv : 0.0f;
    out3[i] = make_float4(bow, bow, bow, bow);
}

extern "C" void kernel_launch(void* const* d_in, const int* in_sizes, int n_in,
                              void* d_out, int out_size, void* d_ws, size_t ws_size,
                              hipStream_t stream) {
    const float4* anchors = (const float4*)d_in[0];
    const float4* gt      = (const float4*)d_in[1];
    const float*  iminfo  = (const float*)d_in[2];
    const float*  noise   = (const float*)d_in[3];

    float*  out0 = (float*)d_out;                  // NN
    float4* out1 = (float4*)(out0 + NN);           // NN x 4
    float4* out2 = (float4*)(out0 + NN + 4 * NN);  // NN x 4
    float4* out3 = (float4*)(out0 + NN + 8 * NN);  // NN x 4

    // value buckets live in the (not-yet-written) out1/out2 region of d_out
    float* bfv = out0 + NN;                        // BINS*BCAP floats = 2MB
    float* bbv = bfv + BINS * BCAP;                // 2MB more (still < out1+out2 span)

    char* ws = (char*)d_ws;
    unsigned* sc   = (unsigned*)ws;                         // 128 u32 (S_WL at +256B)
    unsigned* gtm  = (unsigned*)(ws + 512);                 // 128 u32
    float*    sgmv = (float*)(ws + 1024);                   // 128 f32
    float*    sgar = (float*)(ws + 1536);                   // 128 f32
    float4*   sgt  = (float4*)(ws + 2048);                  // 128 f4 -> ends 4096
    unsigned* hfv  = (unsigned*)(ws + 4096);                // 8192 u32
    unsigned* hbv  = hfv + BINS;                            // 8192 u32 -> ends 69632
    float* labels  = (float*)(ws + 69632);                  // NN f32
    float* maxov   = labels + NN;                           // NN f32
    unsigned char* argm = (unsigned char*)(maxov + NN);     // NN u8
    unsigned* wl   = (unsigned*)(ws + 2143232);             // NN u32 worklist

    k_init<<<68, 256, 0, stream>>>((unsigned*)ws, 17408);   // sc+gtm+sorted+hists
    k_rowcol<<<NBLK, 256, 0, stream>>>(anchors, gt, iminfo, maxov, argm, gtm);
    k_sortgt<<<1, 128, 0, stream>>>(gt, gtm, sgt, sgar, sgmv, sc);
    k_labels_a<<<NBLK, 256, 0, stream>>>(maxov, noise, sc, labels, hfv, hbv, bfv, bbv, wl);
    k_labels_b<<<256, 256, 0, stream>>>(anchors, sgt, sgar, sgmv, maxov, noise, wl,
                                        labels, hfv, hbv, bfv, bbv, sc);
    k_sel<<<1, 256, 0, stream>>>(hfv, bfv, sc, 0);
    k_sel<<<1, 256, 0, stream>>>(hbv, bbv, sc, 1);
    k_final<<<NBLK, 256, 0, stream>>>(anchors, gt, noise, labels, argm, maxov, sc,
                                      out0, out1, out2, out3);
}